// Round 6
// baseline (291.572 us; speedup 1.0000x reference)
//
#include <hip/hip_runtime.h>
#include <cstdint>
#include <cstddef>

namespace {

constexpr int kB    = 64;
constexpr int kN    = 1024;
constexpr int kE    = 655360;
constexpr int kEper = kE / kB;     // 10240
constexpr int kH    = 128;
constexpr int kK1   = 820;
constexpr int kK2   = 656;
constexpr int kM1   = kB * kN;     // 65536
constexpr int kM2   = kB * kK1;    // 52480
constexpr int kM3   = kB * kK2;    // 41984
constexpr int kRChunks = 16;       // readout row-chunks per graph

typedef __attribute__((ext_vector_type(8))) short bf16x8;
typedef __attribute__((ext_vector_type(4))) float f32x4;

__device__ inline ushort f2bf(float f) {            // fp32 -> bf16 RNE bits
  uint u = __float_as_uint(f);
  return (ushort)((u + 0x7fffu + ((u >> 16) & 1u)) >> 16);
}
__device__ inline float bf2f(ushort s) { return __uint_as_float(((uint)s) << 16); }

// packed hi/lo split of 8 floats via v_cvt_pk_bf16_f32 (2 f32 -> 1 u32 of
// 2 bf16, consecutive packing verified learn_hip m214v22). ~24 VALU per 8
// elems vs ~70 for the scalar f2bf chain.
__device__ inline void cvt8(const float* f, uint* hh, uint* ll) {
#pragma unroll
  for (int i = 0; i < 4; ++i) {
    uint h;
    asm("v_cvt_pk_bf16_f32 %0, %1, %2" : "=v"(h) : "v"(f[2 * i]), "v"(f[2 * i + 1]));
    const float r0 = __uint_as_float(h << 16);
    const float r1 = __uint_as_float(h & 0xFFFF0000u);
    const float d0 = f[2 * i] - r0;
    const float d1 = f[2 * i + 1] - r1;
    uint l;
    asm("v_cvt_pk_bf16_f32 %0, %1, %2" : "=v"(l) : "v"(d0), "v"(d1));
    hh[i] = h; ll[i] = l;
  }
}

// inclusive block scan over 1024 threads: wave shfl-scan + 16-wavesum scan.
__device__ inline int block_scan_1024(int v, int* wsum /* LDS int[16] */) {
  const int lane = threadIdx.x & 63;
  const int w    = threadIdx.x >> 6;
#pragma unroll
  for (int off = 1; off < 64; off <<= 1) {
    const int n = __shfl_up(v, off);
    if (lane >= off) v += n;
  }
  if (lane == 63) wsum[w] = v;
  __syncthreads();
  if (w == 0) {
    int s = (lane < 16) ? wsum[lane] : 0;
#pragma unroll
    for (int off = 1; off < 16; off <<= 1) {
      const int n = __shfl_up(s, off);
      if (lane >= off) s += n;
    }
    if (lane < 16) wsum[lane] = s;
  }
  __syncthreads();
  if (w > 0) v += wsum[w - 1];
  return v;
}

// ===== fused CSR build + weight prep (R16): one launch, 129 blocks =====
// blocks 0..63: per-graph LDS counting-sort CSR (ent = graph-local src ids).
// blocks 64..127: W^T hi/lo split (4 old 256-thr jobs per block, barrier-free).
// block 128: pw normalize, barrier-free (redundant 128-sum per thread).
__global__ __launch_bounds__(1024)
void build_prep(const int* __restrict__ src, const int* __restrict__ dst,
                int* __restrict__ coff, int* __restrict__ ccur,
                int* __restrict__ ent,
                const float* __restrict__ Wl1, const float* __restrict__ Wr1,
                const float* __restrict__ Wl2, const float* __restrict__ Wr2,
                const float* __restrict__ pw1, const float* __restrict__ pw2,
                ushort* __restrict__ W1h, ushort* __restrict__ W1l,
                ushort* __restrict__ W2h, ushort* __restrict__ W2l,
                float* __restrict__ pwn1, float* __restrict__ pwn2) {
  const int b   = blockIdx.x;
  const int tid = threadIdx.x;
  if (b >= 128) {                                    // pw normalize
    if (tid >= 256) return;
    const float* pw = (tid < 128) ? pw1 : pw2;
    float* o        = (tid < 128) ? pwn1 : pwn2;
    const int j = tid & 127;
    float sum = 0.0f;
    for (int k = 0; k < 128; ++k) { const float v = pw[k]; sum += v * v; }
    o[j] = pw[j] / sqrtf(sum);
    return;
  }
  if (b >= 64) {                                     // weight split
    const int ob  = (b - 64) * 4 + (tid >> 8);       // old prep block 0..255
    const bool l2 = ob >= 128;
    const int idx = (ob & 127) * 256 + (tid & 255);  // 0..32767
    const int n = idx >> 8, k = idx & 255;
    const float* Wl = l2 ? Wl2 : Wl1;
    const float* Wr = l2 ? Wr2 : Wr1;
    const float w = (k < 128) ? Wl[k * kH + n] : Wr[(k - 128) * kH + n];
    const ushort h = f2bf(w);
    (l2 ? W2h : W1h)[n * 256 + k] = h;
    (l2 ? W2l : W1l)[n * 256 + k] = f2bf(w - bf2f(h));
    return;
  }
  // ---- CSR build for graph b ----
  __shared__ int cnt[1024];
  __shared__ int wsum[16];
  const int g = b;
  const int ebase = g * kEper;
  cnt[tid] = 0;
  __syncthreads();
  for (int e = tid; e < kEper; e += 1024)
    atomicAdd(&cnt[dst[ebase + e] & (kN - 1)], 1);
  __syncthreads();
  const int dg   = cnt[tid];
  const int incl = block_scan_1024(dg, wsum);        // internal barriers
  const int start = ebase + incl - dg;               // exclusive scan
  coff[g * kN + tid] = start;
  ccur[g * kN + tid] = start + dg;                   // end offset
  __syncthreads();
  cnt[tid] = start;                                  // repurpose as cursor
  __syncthreads();
  for (int e = tid; e < kEper; e += 1024) {
    const int d   = dst[ebase + e] & (kN - 1);
    const int pos = atomicAdd(&cnt[d], 1);
    ent[pos] = src[ebase + e] & (kN - 1);
  }
}

// ================= LDS-staged gather-mean (v2) =================
// block = (graph, 16-col chunk); 64 KB feature slab in LDS; 4-lane group per
// node, one ds_read_b128 slot per edge (1024 B payload/wave-instr), edge ids
// hw-broadcast (same addr per 4 lanes), prefetched one body ahead.
__global__ __launch_bounds__(1024, 8)
void gather1_lds(const float* __restrict__ feat, const int* __restrict__ ent,
                 const int* __restrict__ off, const int* __restrict__ cursor,
                 float* __restrict__ aggout) {
  __shared__ float cache[1024 * 16];                 // 64 KB, stride 16 floats
  const int xcd   = blockIdx.x & 7;
  const int local = blockIdx.x >> 3;
  const int graph = xcd * 8 + (local >> 3);
  const int chunk = local & 7;
  const int tid   = threadIdx.x;
  const int gbase = graph << 10;

  // ---- stage: 1024 rows x 16 cols (64-B segments, 4 lanes/row) ----
#pragma unroll
  for (int ps = 0; ps < 4; ++ps) {
    const int row = ps * 256 + (tid >> 2);
    const int q   = (tid & 3) * 4;
    const float4 v = *(const float4*)(feat + (size_t)(gbase + row) * kH + chunk * 16 + q);
    *(float4*)&cache[row * 16 + q] = v;
  }
  __syncthreads();

  const int grp = tid >> 2;            // group id 0..255 = node within iter
  const int q4  = (tid & 3) * 4;       // this lane's 4 cols inside the chunk

  for (int it = 0; it < 4; ++it) {
    const int lnode = it * 256 + grp;
    const int node  = gbase + lnode;
    const int o0 = off[node];
    const int o1 = cursor[node];
    const int deg = o1 - o0;
    float4 acc = make_float4(0.f, 0.f, 0.f, 0.f);
    int pf[4];
#pragma unroll
    for (int i = 0; i < 4; ++i) pf[i] = (o0 + i < o1) ? ent[o0 + i] : 0;
    for (int eb = 0; eb < deg; eb += 4) {
      int nx[4];
#pragma unroll
      for (int i = 0; i < 4; ++i) {
        const int idx = o0 + eb + 4 + i;
        nx[i] = (idx < o1) ? ent[idx] : 0;
      }
#pragma unroll
      for (int i = 0; i < 4; ++i) {
        const float m = (eb + i < deg) ? 1.0f : 0.0f;   // mask tail (row 0 reads broadcast, free)
        const float4 v = *(const float4*)&cache[pf[i] * 16 + q4];
        acc.x = fmaf(v.x, m, acc.x);
        acc.y = fmaf(v.y, m, acc.y);
        acc.z = fmaf(v.z, m, acc.z);
        acc.w = fmaf(v.w, m, acc.w);
      }
#pragma unroll
      for (int i = 0; i < 4; ++i) pf[i] = nx[i];
    }
    const float r = 1.0f / fmaxf((float)deg, 1.0f);
    const f32x4 res = {acc.x * r, acc.y * r, acc.z * r, acc.w * r};
    __builtin_nontemporal_store(res, (f32x4*)(aggout + (size_t)node * kH + chunk * 16 + q4));
  }
}

// layer-2 variant (v3): raw ent (4 B/edge) + per-graph gated-score table gsg
// staged in LDS (4 KB): gs[l] = keep ? sc+2 : 0. Per edge: one ds_read_b128
// (features) + one ds_read_b32 (gate). cnt counts kept edges only.
__global__ __launch_bounds__(1024, 8)
void gather2_lds(const float* __restrict__ feat, const int* __restrict__ ent,
                 const int* __restrict__ off, const int* __restrict__ cursor,
                 const int* __restrict__ perm, const float* __restrict__ gsg,
                 float* __restrict__ aggout) {
  __shared__ float cache[1024 * 16];                 // 64 KB
  __shared__ float gs[1024];                         // 4 KB gated scores
  const int xcd   = blockIdx.x & 7;
  const int local = blockIdx.x >> 3;
  const int graph = xcd * 8 + (local >> 3);
  const int chunk = local & 7;
  const int tid   = threadIdx.x;
  const int gbase = graph << 10;

#pragma unroll
  for (int ps = 0; ps < 4; ++ps) {
    const int row = ps * 256 + (tid >> 2);
    const int q   = (tid & 3) * 4;
    const float4 v = *(const float4*)(feat + (size_t)(gbase + row) * kH + chunk * 16 + q);
    *(float4*)&cache[row * 16 + q] = v;
  }
  gs[tid] = gsg[gbase + tid];
  __syncthreads();

  const int grp = tid >> 2;
  const int q4  = (tid & 3) * 4;

  for (int it = 0; it < 4; ++it) {
    const int lnode = it * 256 + grp;                // valid < kK1 (820)
    int o0 = 0, o1 = 0;
    if (lnode < kK1) {
      const int orig = perm[graph * kK1 + lnode];
      o0 = off[orig];
      o1 = cursor[orig];
    }
    const int deg = o1 - o0;
    float4 acc = make_float4(0.f, 0.f, 0.f, 0.f);
    int cnt = 0;
    int pf[4];
#pragma unroll
    for (int i = 0; i < 4; ++i) pf[i] = (o0 + i < o1) ? ent[o0 + i] : 0;
    for (int eb = 0; eb < deg; eb += 4) {
      int nx[4];
#pragma unroll
      for (int i = 0; i < 4; ++i) {
        const int idx = o0 + eb + 4 + i;
        nx[i] = (idx < o1) ? ent[idx] : 0;
      }
#pragma unroll
      for (int i = 0; i < 4; ++i) {
        const float raw  = gs[pf[i]];
        const bool  kept = (raw > 0.5f) && (eb + i < deg);
        const float s    = kept ? raw - 2.0f : 0.0f;
        cnt += kept ? 1 : 0;
        const float4 v = *(const float4*)&cache[pf[i] * 16 + q4];
        acc.x = fmaf(v.x, s, acc.x);
        acc.y = fmaf(v.y, s, acc.y);
        acc.z = fmaf(v.z, s, acc.z);
        acc.w = fmaf(v.w, s, acc.w);
      }
#pragma unroll
      for (int i = 0; i < 4; ++i) pf[i] = nx[i];
    }
    const float r = 1.0f / fmaxf((float)cnt, 1.0f);
    const f32x4 res = {acc.x * r, acc.y * r, acc.z * r, acc.w * r};
    if (lnode < kK1)
      __builtin_nontemporal_store(res,
          (f32x4*)(aggout + (size_t)(graph * kK1 + lnode) * kH + chunk * 16 + q4));
  }
}

// ============ split-bf16 MFMA SAGE GEMM + fused score (v2, R16) ============
// 64x128 tile, 4 waves 2x2, wave tile 32x64. R16 staging redesign:
// - A converted with v_cvt_pk_bf16_f32 (24 VALU/8 elems vs ~70), written as
//   one 16B uint4 per array; double-buffered -> ONE barrier per k-step.
// - W fragments read DIRECT from global (WTh/WTl are 256 KB, L2-resident
//   across all blocks) -> all W LDS staging deleted (LDS ops 24 -> 6).
// - perm/gsc row lookup hoisted out of the k-loop (was reloaded 4x).
__global__ __launch_bounds__(256)
void sage_gemm_mfma(const float* __restrict__ meanb, const float* __restrict__ xsrc,
                    const int* __restrict__ perm, const float* __restrict__ gsc,
                    const ushort* __restrict__ WTh, const ushort* __restrict__ WTl,
                    const float* __restrict__ bias, const float* __restrict__ pwn,
                    float* __restrict__ outp, float* __restrict__ scr) {
  __shared__ __align__(16) ushort aH[2][64][32];   // [buf][row][k]
  __shared__ __align__(16) ushort aL[2][64][32];
  __shared__ float sdot[64][2];                    // [row][col-half] score partials
  const int tid  = threadIdx.x;
  const int wid  = tid >> 6;
  const int lane = tid & 63;
  const int quad = lane >> 4;
  const int l16  = lane & 15;
  const int rowbase = blockIdx.x * 64;
  const int wr = (wid >> 1) * 32;                  // wave row offset (0/32)
  const int wc = (wid & 1) * 64;                   // wave col offset (0/64)

  // staging: each thread owns one row, 8 consecutive k per step
  const int arow = tid >> 2;                       // 0..63
  const int k8   = (tid & 3) * 8;                  // 0/8/16/24
  const int grow = rowbase + arow;
  int prow = grow; float pscale = 1.0f;
  if (perm) { prow = perm[grow]; pscale = gsc[grow]; }
  const float* mrow = meanb + (size_t)grow * kH;
  const float* xrow = xsrc + (size_t)prow * kH;

  f32x4 acc[2][4];
#pragma unroll
  for (int a = 0; a < 2; ++a)
#pragma unroll
    for (int b = 0; b < 4; ++b) acc[a][b] = (f32x4){0.f, 0.f, 0.f, 0.f};

  for (int s = 0; s < 8; ++s) {                    // 8 k-steps of 32 over K=256
    const bool ismean = s < 4;
    const float* sp = ismean ? mrow : xrow;
    const float sc  = ismean ? 1.0f : pscale;
    const int kloc  = (ismean ? s : s - 4) * 32;
    // ---- stage A (fp32 -> bf16 hi/lo, packed) ----
    const float4 va = *(const float4*)(sp + kloc + k8);
    const float4 vb = *(const float4*)(sp + kloc + k8 + 4);
    float f[8] = {va.x * sc, va.y * sc, va.z * sc, va.w * sc,
                  vb.x * sc, vb.y * sc, vb.z * sc, vb.w * sc};
    uint hh[4], ll[4];
    cvt8(f, hh, ll);
    *(uint4*)&aH[s & 1][arow][k8] = make_uint4(hh[0], hh[1], hh[2], hh[3]);
    *(uint4*)&aL[s & 1][arow][k8] = make_uint4(ll[0], ll[1], ll[2], ll[3]);
    __syncthreads();                               // single barrier (dbuf)
    // ---- A fragments from LDS ----
    bf16x8 afh[2], afl[2];
#pragma unroll
    for (int rt = 0; rt < 2; ++rt) {
      afh[rt] = *(const bf16x8*)&aH[s & 1][wr + rt * 16 + l16][quad * 8];
      afl[rt] = *(const bf16x8*)&aL[s & 1][wr + rt * 16 + l16][quad * 8];
    }
    // ---- W fragments direct from global (L2-resident) ----
    const int kbase = s * 32;
    bf16x8 bh[4], bl[4];
#pragma unroll
    for (int ct = 0; ct < 4; ++ct) {
      const size_t wo = (size_t)(wc + ct * 16 + l16) * 256 + kbase + quad * 8;
      bh[ct] = *(const bf16x8*)(WTh + wo);
      bl[ct] = *(const bf16x8*)(WTl + wo);
    }
#pragma unroll
    for (int ct = 0; ct < 4; ++ct) {
#pragma unroll
      for (int rt = 0; rt < 2; ++rt) {
        acc[rt][ct] = __builtin_amdgcn_mfma_f32_16x16x32_bf16(afh[rt], bh[ct], acc[rt][ct], 0, 0, 0);
        acc[rt][ct] = __builtin_amdgcn_mfma_f32_16x16x32_bf16(afh[rt], bl[ct], acc[rt][ct], 0, 0, 0);
        acc[rt][ct] = __builtin_amdgcn_mfma_f32_16x16x32_bf16(afl[rt], bh[ct], acc[rt][ct], 0, 0, 0);
      }
    }
  }
  // ---- epilogue: bias + relu + store + fused score (64-col partial/wave) ----
  float bv[4], pwv[4];
#pragma unroll
  for (int ct = 0; ct < 4; ++ct) {
    const int col = wc + ct * 16 + l16;
    bv[ct]  = bias[col];
    pwv[ct] = pwn[col];
  }
  float dot[2][4];
#pragma unroll
  for (int rt = 0; rt < 2; ++rt)
#pragma unroll
    for (int reg = 0; reg < 4; ++reg) dot[rt][reg] = 0.0f;
#pragma unroll
  for (int ct = 0; ct < 4; ++ct) {
    const int col = wc + ct * 16 + l16;
#pragma unroll
    for (int rt = 0; rt < 2; ++rt) {
#pragma unroll
      for (int reg = 0; reg < 4; ++reg) {
        const int row = rowbase + wr + rt * 16 + quad * 4 + reg;
        const float o = fmaxf(acc[rt][ct][reg] + bv[ct], 0.0f);
        outp[(size_t)row * kH + col] = o;
        dot[rt][reg] += o * pwv[ct];
      }
    }
  }
#pragma unroll
  for (int rt = 0; rt < 2; ++rt) {
#pragma unroll
    for (int reg = 0; reg < 4; ++reg) {
      float d = dot[rt][reg];
      d += __shfl_xor(d, 1);
      d += __shfl_xor(d, 2);
      d += __shfl_xor(d, 4);
      d += __shfl_xor(d, 8);
      if (l16 == 0) sdot[wr + rt * 16 + quad * 4 + reg][wc >> 6] = d;
    }
  }
  __syncthreads();
  if (tid < 64) scr[rowbase + tid] = tanhf(sdot[tid][0] + sdot[tid][1]);
}

// ================= fused top-K rank + compaction (radix select) =========
// 4-pass byte radix-select on order-preserving uint keys. Histogram from
// registers; bin suffix-scan inside wave 0 only. Yields threshold key T and
// rem = #(==T) to keep (lowest-index-first). One packed block scan of
// (gt<<11)|eq gives keep AND compaction position.
__global__ __launch_bounds__(1024)
void rank_compact(const float* __restrict__ scr, int n_per, int K,
                  int* __restrict__ perm, float* __restrict__ gsc,
                  float* __restrict__ gsg) {
  __shared__ int hist[256];
  __shared__ int wsum[16];
  __shared__ uint bT;
  __shared__ int bRem;
  const int g = blockIdx.x, tid = threadIdx.x;
  const float sc = (tid < n_per) ? scr[g * n_per + tid] : -3e30f;  // pad never wins
  const uint bits = __float_as_uint(sc);
  const uint key = (bits & 0x80000000u) ? ~bits : (bits | 0x80000000u);

  uint prefix = 0;
  int rem = K;
#pragma unroll
  for (int shift = 24; shift >= 0; shift -= 8) {
    if (tid < 256) hist[tid] = 0;
    __syncthreads();
    const uint mask = (shift == 24) ? 0u : (0xFFFFFFFFu << (shift + 8));
    if ((key & mask) == prefix)
      atomicAdd(&hist[(key >> shift) & 255], 1);
    __syncthreads();
    if (tid < 64) {
      const int h0 = hist[4 * tid + 0], h1 = hist[4 * tid + 1];
      const int h2 = hist[4 * tid + 2], h3 = hist[4 * tid + 3];
      const int loc = h0 + h1 + h2 + h3;
      int suf = loc;                       // inclusive suffix sum over lanes
#pragma unroll
      for (int d = 1; d < 64; d <<= 1) {
        const int o = __shfl_down(suf, d);
        if (tid + d < 64) suf += o;
      }
      const int above = suf - loc;         // strictly-higher lanes
      int hs[5];
      hs[4] = above;
      hs[3] = above + h3;
      hs[2] = hs[3] + h2;
      hs[1] = hs[2] + h1;
      hs[0] = hs[1] + h0;
#pragma unroll
      for (int q = 0; q < 4; ++q) {
        if (hs[q] >= rem && hs[q + 1] < rem) {   // unique crossing bin
          bT   = prefix | ((uint)(4 * tid + q) << shift);
          bRem = rem - hs[q + 1];
        }
      }
    }
    __syncthreads();
    prefix = bT;
    rem    = bRem;
  }
  // prefix == key of K-th largest; rem == #(==T) to keep (by lowest index).
  const int gt = (key > prefix) ? 1 : 0;
  const int eq = (key == prefix) ? 1 : 0;
  const int incl = block_scan_1024((gt << 11) | eq, wsum);   // internal barriers
  const int excl = incl - ((gt << 11) | eq);
  const int gt_excl = excl >> 11;
  const int eq_excl = excl & 2047;
  const int keep = (tid < n_per) && (gt || (eq && eq_excl < rem));
  if (keep) {
    const int pos = gt_excl + min(eq_excl, rem);
    perm[g * K + pos] = g * n_per + tid;
    gsc[g * K + pos]  = sc;
  }
  if (gsg) gsg[g * kN + tid] = keep ? sc + 2.0f : 0.0f;
}

// ---- readout stage 1: per-(graph, row-chunk) partial mean/max over gated rows ----
__global__ __launch_bounds__(256)
void readout_part(const float* __restrict__ h, const int* __restrict__ perm,
                  const float* __restrict__ gsc, int K,
                  float* __restrict__ psum, float* __restrict__ pmax) {
  const int g     = blockIdx.x >> 4;
  const int chunk = blockIdx.x & (kRChunks - 1);
  const int j     = threadIdx.x & 127;
  const int part  = threadIdx.x >> 7;            // 2 parts
  const int rows  = (K + kRChunks - 1) / kRChunks;
  const int r0 = chunk * rows;
  const int r1 = min(r0 + rows, K);
  float sum = 0.0f, mx = -1e30f;
  for (int r = r0 + part; r < r1; r += 2) {
    const int   row = perm[g * K + r];
    const float sc  = gsc[g * K + r];
    const float v   = h[(size_t)row * kH + j] * sc;
    sum += v;
    mx = fmaxf(mx, v);
  }
  __shared__ float ss[2][128], sm[2][128];
  ss[part][j] = sum;
  sm[part][j] = mx;
  __syncthreads();
  if (part == 0) {
    sum += ss[1][j];
    mx = fmaxf(mx, sm[1][j]);
    psum[(size_t)blockIdx.x * 128 + j] = sum;
    pmax[(size_t)blockIdx.x * 128 + j] = mx;
  }
}

// ---- fused: combine readout chunks (both layers) + 2-layer MLP head ----
__global__ __launch_bounds__(128)
void final_mlp(const float* __restrict__ ps1, const float* __restrict__ pm1,
               const float* __restrict__ ps2, const float* __restrict__ pm2,
               const float* __restrict__ fW1, const float* __restrict__ fb1,
               const float* __restrict__ fW2, const float* __restrict__ fb2,
               float* __restrict__ out) {
  __shared__ float xx[256];
  __shared__ float z[128];
  const int g = blockIdx.x, tid = threadIdx.x;
  float s1 = 0.f, m1 = -1e30f, s2 = 0.f, m2 = -1e30f;
#pragma unroll
  for (int c = 0; c < kRChunks; ++c) {
    s1 += ps1[(size_t)(g * kRChunks + c) * 128 + tid];
    m1 = fmaxf(m1, pm1[(size_t)(g * kRChunks + c) * 128 + tid]);
    s2 += ps2[(size_t)(g * kRChunks + c) * 128 + tid];
    m2 = fmaxf(m2, pm2[(size_t)(g * kRChunks + c) * 128 + tid]);
  }
  xx[tid]       = s1 / (float)kK1 + s2 / (float)kK2;
  xx[tid + 128] = m1 + m2;
  __syncthreads();
  float a = fb1[tid];
  for (int k = 0; k < 256; ++k) a += xx[k] * fW1[k * 128 + tid];
  z[tid] = fmaxf(a, 0.0f);
  __syncthreads();
  if (tid < 10) {
    float o = fb2[tid];
    for (int k = 0; k < 128; ++k) o += z[k] * fW2[k * 10 + tid];
    out[g * 10 + tid] = o;
  }
}

}  // namespace

extern "C" void kernel_launch(void* const* d_in, const int* in_sizes, int n_in,
                              void* d_out, int out_size, void* d_ws, size_t ws_size,
                              hipStream_t stream) {
  const float* x   = (const float*)d_in[0];
  const int*   ei  = (const int*)d_in[1];
  const float* Wl1 = (const float*)d_in[3];
  const float* bl1 = (const float*)d_in[4];
  const float* Wr1 = (const float*)d_in[5];
  const float* Wl2 = (const float*)d_in[6];
  const float* bl2 = (const float*)d_in[7];
  const float* Wr2 = (const float*)d_in[8];
  const float* pw1 = (const float*)d_in[9];
  const float* pw2 = (const float*)d_in[10];
  const float* fW1 = (const float*)d_in[11];
  const float* fb1 = (const float*)d_in[12];
  const float* fW2 = (const float*)d_in[13];
  const float* fb2 = (const float*)d_in[14];
  const int* src = ei;
  const int* dst = ei + kE;
  (void)in_sizes; (void)n_in; (void)out_size; (void)ws_size;

  char* wsb = (char*)d_ws;
  size_t off_b = 0;
  auto alloc = [&](size_t bytes) {
    void* p = wsb + off_b;
    off_b += (bytes + 255) & ~(size_t)255;
    return p;
  };
  float* bufA = (float*)alloc((size_t)kM1 * kH * 4);  // mean1 -> mean2
  float* bufB = (float*)alloc((size_t)kM1 * kH * 4);  // h1
  float* bufC = (float*)alloc((size_t)kM2 * kH * 4);  // h2
  int*   coff = (int*)alloc((size_t)kM1 * 4);
  int*   ccur = (int*)alloc((size_t)kM1 * 4);
  int*   ent  = (int*)alloc((size_t)kE * 4);
  float* scr  = (float*)alloc((size_t)kM1 * 4);
  float* gsg  = (float*)alloc((size_t)kM1 * 4);
  int*   perm1= (int*)alloc((size_t)kM2 * 4);
  float* gsc1 = (float*)alloc((size_t)kM2 * 4);
  int*   perm2= (int*)alloc((size_t)kM3 * 4);
  float* gsc2 = (float*)alloc((size_t)kM3 * 4);
  float* psum1= (float*)alloc((size_t)kB * kRChunks * 128 * 4);
  float* pmax1= (float*)alloc((size_t)kB * kRChunks * 128 * 4);
  float* psum2= (float*)alloc((size_t)kB * kRChunks * 128 * 4);
  float* pmax2= (float*)alloc((size_t)kB * kRChunks * 128 * 4);
  ushort* wt1h = (ushort*)alloc((size_t)128 * 256 * 2);
  ushort* wt1l = (ushort*)alloc((size_t)128 * 256 * 2);
  ushort* wt2h = (ushort*)alloc((size_t)128 * 256 * 2);
  ushort* wt2l = (ushort*)alloc((size_t)128 * 256 * 2);
  float* pwn1 = (float*)alloc(128 * 4);
  float* pwn2 = (float*)alloc(128 * 4);

  // ---------------- fused CSR build + prep ----------------
  build_prep<<<129, 1024, 0, stream>>>(src, dst, coff, ccur, ent,
                                       Wl1, Wr1, Wl2, Wr2, pw1, pw2,
                                       wt1h, wt1l, wt2h, wt2l, pwn1, pwn2);

  // ---------------- layer 1 ----------------
  gather1_lds<<<kB * 8, 1024, 0, stream>>>(x, ent, coff, ccur, bufA);
  sage_gemm_mfma<<<kM1 / 64, 256, 0, stream>>>(bufA, x, nullptr, nullptr,
                                               wt1h, wt1l, bl1, pwn1, bufB, scr);
  rank_compact<<<kB, 1024, 0, stream>>>(scr, kN, kK1, perm1, gsc1, gsg);
  readout_part<<<kB * kRChunks, 256, 0, stream>>>(bufB, perm1, gsc1, kK1, psum1, pmax1);

  // ---------------- layer 2 (reuses layer-1 CSR; gate staged in gather2 LDS) ----
  gather2_lds<<<kB * 8, 1024, 0, stream>>>(bufB, ent, coff, ccur, perm1, gsg, bufA);
  sage_gemm_mfma<<<kM2 / 64, 256, 0, stream>>>(bufA, bufB, perm1, gsc1,
                                               wt2h, wt2l, bl2, pwn2, bufC, scr);
  rank_compact<<<kB, 1024, 0, stream>>>(scr, kK1, kK2, perm2, gsc2, nullptr);
  readout_part<<<kB * kRChunks, 256, 0, stream>>>(bufC, perm2, gsc2, kK2, psum2, pmax2);

  // ---------------- head ----------------
  final_mlp<<<kB, 128, 0, stream>>>(psum1, pmax1, psum2, pmax2,
                                    fW1, fb1, fW2, fb2, (float*)d_out);
}